// Round 1
// baseline (90.717 us; speedup 1.0000x reference)
//
#include <hip/hip_runtime.h>
#include <math.h>

#define B_ 2
#define SQ_ 1024
#define SK_ 1024
#define D_ 64
#define DV_ 64
#define QB 4
#define TPB 256
#define NEGC (-1e9f)

__global__ __launch_bounds__(TPB) void manh_attn_kernel(
    const float* __restrict__ qg, const float* __restrict__ kg,
    const float* __restrict__ vg, const int* __restrict__ maskg,
    float* __restrict__ outg) {
  __shared__ float qs[QB * D_];        // 1 KB: 4 query rows
  __shared__ float p[QB][SK_];         // 16 KB: probabilities
  __shared__ float pv[16][QB][DV_];    // 16 KB: PV chunk partials
  __shared__ float redm[4][QB];        // per-wave max
  __shared__ float redl[4][QB];        // per-wave sum

  const int tid = threadIdx.x;
  const int b = blockIdx.x / (SQ_ / QB);
  const int q0 = (blockIdx.x % (SQ_ / QB)) * QB;

  // 4 query rows are contiguous: 256 floats == 256 threads
  qs[tid] = qg[((size_t)b * SQ_ + q0) * D_ + tid];
  __syncthreads();

  const float* kb = kg + (size_t)b * SK_ * D_;
  const int* mb = maskg + (size_t)b * SK_;

  float sreg[4][QB];
  float lmax[QB];
#pragma unroll
  for (int qq = 0; qq < QB; ++qq) lmax[qq] = -INFINITY;

  // ---- Phase 1: scores ----
#pragma unroll
  for (int j = 0; j < 4; ++j) {
    const int kk = tid + 256 * j;
    const float4* kr = (const float4*)(kb + (size_t)kk * D_);
    float dist[QB];
#pragma unroll
    for (int qq = 0; qq < QB; ++qq) dist[qq] = 0.f;
#pragma unroll
    for (int i = 0; i < 16; ++i) {
      float4 k4 = kr[i];
#pragma unroll
      for (int qq = 0; qq < QB; ++qq) {
        float4 q4 = ((const float4*)qs)[qq * 16 + i];
        dist[qq] += fabsf(q4.x - k4.x) + fabsf(q4.y - k4.y) +
                    fabsf(q4.z - k4.z) + fabsf(q4.w - k4.w);
      }
    }
    const int mk = mb[kk];
#pragma unroll
    for (int qq = 0; qq < QB; ++qq) {
      float s = (mk == 0) ? NEGC : -dist[qq];
      sreg[j][qq] = s;
      lmax[qq] = fmaxf(lmax[qq], s);
    }
  }

  // block max reduction
#pragma unroll
  for (int off = 32; off > 0; off >>= 1) {
#pragma unroll
    for (int qq = 0; qq < QB; ++qq)
      lmax[qq] = fmaxf(lmax[qq], __shfl_down(lmax[qq], off, 64));
  }
  if ((tid & 63) == 0) {
#pragma unroll
    for (int qq = 0; qq < QB; ++qq) redm[tid >> 6][qq] = lmax[qq];
  }
  __syncthreads();
  float m[QB];
#pragma unroll
  for (int qq = 0; qq < QB; ++qq)
    m[qq] = fmaxf(fmaxf(redm[0][qq], redm[1][qq]),
                  fmaxf(redm[2][qq], redm[3][qq]));

  // exp + sum
  float lsum[QB];
#pragma unroll
  for (int qq = 0; qq < QB; ++qq) lsum[qq] = 0.f;
#pragma unroll
  for (int j = 0; j < 4; ++j) {
    const int kk = tid + 256 * j;
#pragma unroll
    for (int qq = 0; qq < QB; ++qq) {
      float e = __expf(sreg[j][qq] - m[qq]);
      p[qq][kk] = e;
      lsum[qq] += e;
    }
  }
#pragma unroll
  for (int off = 32; off > 0; off >>= 1) {
#pragma unroll
    for (int qq = 0; qq < QB; ++qq)
      lsum[qq] += __shfl_down(lsum[qq], off, 64);
  }
  if ((tid & 63) == 0) {
#pragma unroll
    for (int qq = 0; qq < QB; ++qq) redl[tid >> 6][qq] = lsum[qq];
  }
  __syncthreads();  // covers p[] writes + redl writes

  // ---- Phase 2: PV ----
  const int col = tid & 15;    // float4 column of DV
  const int chunk = tid >> 4;  // 16 chunks x 64 keys
  const float* vb = vg + (size_t)b * SK_ * DV_;
  float4 acc[QB];
#pragma unroll
  for (int qq = 0; qq < QB; ++qq) acc[qq] = make_float4(0.f, 0.f, 0.f, 0.f);

#pragma unroll 8
  for (int t = 0; t < 64; ++t) {
    const int kk = chunk * 64 + t;
    float4 v4 = ((const float4*)(vb + (size_t)kk * DV_))[col];
#pragma unroll
    for (int qq = 0; qq < QB; ++qq) {
      float pw = p[qq][kk];
      acc[qq].x += pw * v4.x;
      acc[qq].y += pw * v4.y;
      acc[qq].z += pw * v4.z;
      acc[qq].w += pw * v4.w;
    }
  }
#pragma unroll
  for (int qq = 0; qq < QB; ++qq)
    ((float4*)&pv[chunk][qq][0])[col] = acc[qq];
  __syncthreads();

  // final reduce + normalize + store: 256 threads = 4 queries x 64 dims
  const int qq2 = tid >> 6;
  const int d2 = tid & 63;
  float s = 0.f;
#pragma unroll
  for (int c = 0; c < 16; ++c) s += pv[c][qq2][d2];
  const float linv =
      1.f / (redl[0][qq2] + redl[1][qq2] + redl[2][qq2] + redl[3][qq2]);
  outg[((size_t)b * SQ_ + q0 + qq2) * DV_ + d2] = s * linv;
}

extern "C" void kernel_launch(void* const* d_in, const int* in_sizes, int n_in,
                              void* d_out, int out_size, void* d_ws,
                              size_t ws_size, hipStream_t stream) {
  const float* q = (const float*)d_in[0];
  const float* k = (const float*)d_in[1];
  const float* v = (const float*)d_in[2];
  const int* mask = (const int*)d_in[3];
  float* out = (float*)d_out;
  dim3 grid(B_ * (SQ_ / QB));
  manh_attn_kernel<<<grid, TPB, 0, stream>>>(q, k, v, mask, out);
}

// Round 2
// 85.478 us; speedup vs baseline: 1.0613x; 1.0613x over previous
//
#include <hip/hip_runtime.h>
#include <math.h>

#define B_ 2
#define SQ_ 1024
#define SK_ 1024
#define D_ 64
#define DV_ 64
#define QB 4
#define TPB 256
#define NEGC (-1e9f)

__global__ __launch_bounds__(TPB, 4) void manh_attn_kernel(
    const float* __restrict__ qg, const float* __restrict__ kg,
    const float* __restrict__ vg, const int* __restrict__ maskg,
    float* __restrict__ outg) {
  __shared__ float4 qs4[QB * 16];     // 1 KB: 4 query rows as float4[16]
  __shared__ float4 p4[SK_];          // 16 KB: probs, key-major [kk][4q]
  __shared__ float pv[16][QB][DV_];   // 16 KB: PV chunk partials
  __shared__ float redm[4][QB];
  __shared__ float redl[4][QB];

  const int tid = threadIdx.x;
  const int b = blockIdx.x >> 8;            // grid = 512
  const int q0 = (blockIdx.x & 255) * QB;

  // stage 4 query rows (256 floats == 256 threads)
  ((float*)qs4)[tid] = qg[((size_t)b * SQ_ + q0) * D_ + tid];
  __syncthreads();

  const float4* kb4 = (const float4*)(kg + (size_t)b * SK_ * D_);
  const int* mb = maskg + (size_t)b * SK_;

  int mk[4];
#pragma unroll
  for (int j = 0; j < 4; ++j) mk[j] = mb[tid + 256 * j];

  // ---- Phase 1: L1 distances, i (dim-chunk) outer so q reads are
  // wave-uniform broadcasts amortized over 4 keys ----
  float dist[4][QB];
#pragma unroll
  for (int j = 0; j < 4; ++j)
#pragma unroll
    for (int qq = 0; qq < QB; ++qq) dist[j][qq] = 0.f;

#pragma unroll 4
  for (int i = 0; i < 16; ++i) {
    float4 k4[4];
#pragma unroll
    for (int j = 0; j < 4; ++j) k4[j] = kb4[(size_t)(tid + 256 * j) * 16 + i];
    float4 q4[QB];
#pragma unroll
    for (int qq = 0; qq < QB; ++qq) q4[qq] = qs4[qq * 16 + i];  // uniform
#pragma unroll
    for (int j = 0; j < 4; ++j) {
#pragma unroll
      for (int qq = 0; qq < QB; ++qq) {
        dist[j][qq] += fabsf(q4[qq].x - k4[j].x) + fabsf(q4[qq].y - k4[j].y) +
                       fabsf(q4[qq].z - k4[j].z) + fabsf(q4[qq].w - k4[j].w);
      }
    }
  }

  // scores + running max
  float lmax[QB];
#pragma unroll
  for (int qq = 0; qq < QB; ++qq) lmax[qq] = -INFINITY;
#pragma unroll
  for (int j = 0; j < 4; ++j) {
#pragma unroll
    for (int qq = 0; qq < QB; ++qq) {
      float s = (mk[j] == 0) ? NEGC : -dist[j][qq];
      dist[j][qq] = s;  // reuse as score storage
      lmax[qq] = fmaxf(lmax[qq], s);
    }
  }
#pragma unroll
  for (int off = 32; off > 0; off >>= 1)
#pragma unroll
    for (int qq = 0; qq < QB; ++qq)
      lmax[qq] = fmaxf(lmax[qq], __shfl_down(lmax[qq], off, 64));
  if ((tid & 63) == 0)
#pragma unroll
    for (int qq = 0; qq < QB; ++qq) redm[tid >> 6][qq] = lmax[qq];
  __syncthreads();
  float m[QB];
#pragma unroll
  for (int qq = 0; qq < QB; ++qq)
    m[qq] = fmaxf(fmaxf(redm[0][qq], redm[1][qq]),
                  fmaxf(redm[2][qq], redm[3][qq]));

  // exp + sum; probs stored key-major as one float4 per key
  float lsum[QB];
#pragma unroll
  for (int qq = 0; qq < QB; ++qq) lsum[qq] = 0.f;
#pragma unroll
  for (int j = 0; j < 4; ++j) {
    float e[QB];
#pragma unroll
    for (int qq = 0; qq < QB; ++qq) {
      e[qq] = __expf(dist[j][qq] - m[qq]);
      lsum[qq] += e[qq];
    }
    p4[tid + 256 * j] = make_float4(e[0], e[1], e[2], e[3]);
  }
#pragma unroll
  for (int off = 32; off > 0; off >>= 1)
#pragma unroll
    for (int qq = 0; qq < QB; ++qq) lsum[qq] += __shfl_down(lsum[qq], off, 64);
  if ((tid & 63) == 0)
#pragma unroll
    for (int qq = 0; qq < QB; ++qq) redl[tid >> 6][qq] = lsum[qq];
  __syncthreads();  // covers p4 + redl

  // ---- Phase 2: PV. Strided key mapping (kk = t*16 + chunk) keeps the 4
  // in-wave broadcast p4 addresses on distinct banks. ----
  const int col = tid & 15;
  const int chunk = tid >> 4;  // 16 chunks
  const float4* vb4 = (const float4*)(vg + (size_t)b * SK_ * DV_);
  float4 acc[QB];
#pragma unroll
  for (int qq = 0; qq < QB; ++qq) acc[qq] = make_float4(0.f, 0.f, 0.f, 0.f);

#pragma unroll 4
  for (int t = 0; t < 64; ++t) {
    const int kk = t * 16 + chunk;
    float4 v4 = vb4[(size_t)kk * 16 + col];  // wave reads 1 KB contiguous
    float4 pw = p4[kk];                      // 16-lane broadcast, b128
    acc[0].x += pw.x * v4.x; acc[0].y += pw.x * v4.y;
    acc[0].z += pw.x * v4.z; acc[0].w += pw.x * v4.w;
    acc[1].x += pw.y * v4.x; acc[1].y += pw.y * v4.y;
    acc[1].z += pw.y * v4.z; acc[1].w += pw.y * v4.w;
    acc[2].x += pw.z * v4.x; acc[2].y += pw.z * v4.y;
    acc[2].z += pw.z * v4.z; acc[2].w += pw.z * v4.w;
    acc[3].x += pw.w * v4.x; acc[3].y += pw.w * v4.y;
    acc[3].z += pw.w * v4.z; acc[3].w += pw.w * v4.w;
  }
#pragma unroll
  for (int qq = 0; qq < QB; ++qq)
    ((float4*)&pv[chunk][qq][0])[col] = acc[qq];
  __syncthreads();

  // final reduce + normalize + store: 256 threads = 4 q x 64 dims
  const int qq2 = tid >> 6;
  const int d2 = tid & 63;
  float s = 0.f;
#pragma unroll
  for (int c = 0; c < 16; ++c) s += pv[c][qq2][d2];
  const float linv =
      1.f / (redl[0][qq2] + redl[1][qq2] + redl[2][qq2] + redl[3][qq2]);
  outg[((size_t)b * SQ_ + q0 + qq2) * DV_ + d2] = s * linv;
}

extern "C" void kernel_launch(void* const* d_in, const int* in_sizes, int n_in,
                              void* d_out, int out_size, void* d_ws,
                              size_t ws_size, hipStream_t stream) {
  const float* q = (const float*)d_in[0];
  const float* k = (const float*)d_in[1];
  const float* v = (const float*)d_in[2];
  const int* mask = (const int*)d_in[3];
  float* out = (float*)d_out;
  dim3 grid(B_ * (SQ_ / QB));
  manh_attn_kernel<<<grid, TPB, 0, stream>>>(q, k, v, mask, out);
}